// Round 10
// baseline (451.226 us; speedup 1.0000x reference)
//
#include <hip/hip_runtime.h>
#include <math.h>

#define Bn 4096
#define Tn 512
#define Vn 57
#define En 20
#define Hn 128
#define On 18

typedef _Float16 half2v __attribute__((ext_vector_type(2)));

__device__ __forceinline__ float fast_tanh(float x) {
    float e = __expf(2.0f * x);
    return 1.0f - __fdividef(2.0f, e + 1.0f);
}

__device__ __forceinline__ half2v as_h2(unsigned u) {
    union { unsigned u; half2v h; } c; c.u = u; return c.h;
}
__device__ __forceinline__ unsigned pack_h2(float a, float b) {
    union { half2v h; unsigned u; } c;
    c.h = half2v{(_Float16)a, (_Float16)b};
    return c.u;
}

// ---- kernel 1: proj[c][j] = emb[c]@W_ih[j] + b_ih[j] + b_hh[j]  (57x128 f32 -> d_ws)
__global__ void proj_kernel(const float* __restrict__ emb,
                            const float* __restrict__ W_ih,
                            const float* __restrict__ b_ih,
                            const float* __restrict__ b_hh,
                            float* __restrict__ proj)
{
    int idx = blockIdx.x * blockDim.x + threadIdx.x;
    if (idx < Vn * Hn) {
        int c = idx >> 7, j = idx & 127;
        float acc = b_ih[j] + b_hh[j];
        #pragma unroll
        for (int e = 0; e < En; ++e)
            acc += emb[c * En + e] * W_ih[j * En + e];
        proj[idx] = acc;
    }
}

// ---- kernel 2: one wave per batch row, barrier-free recurrence.
// Lane j owns h-elements 2j,2j+1. W_hh rows 2j,2j+1 live in 128 VGPRs (fp16
// half2-packed, loaded once). h replicated to all lanes each step via 16
// broadcast ds_read_b128 from a 256B LDS buffer (same-address = free).
// No __syncthreads in the loop: single-wave block, lgkmcnt orders write->read.
__launch_bounds__(64, 2)   // cap 256 VGPR; demand ~220 -> no spill, 2 waves/SIMD
__global__ void rnn_row_kernel(const int*   __restrict__ x,
                               const int*   __restrict__ xlen,
                               const float* __restrict__ W_hh,
                               const float* __restrict__ W_out,
                               const float* __restrict__ b_out,
                               const float* __restrict__ proj,
                               float*       __restrict__ out)
{
    __shared__ int      sX[Tn];       // this row's token ids
    __shared__ unsigned sH[Hn / 2];   // h fp16: sH[i] = (h[2i], h[2i+1])
    __shared__ float    sHf[Hn];      // final h f32 for the head
    __shared__ float    sLog[On];
    __shared__ float    sRed[1];

    const int row = blockIdx.x;
    const int j   = threadIdx.x;      // 0..63
    const int len = xlen[row];

    // stage token ids (2 x int4 per lane, coalesced)
    #pragma unroll
    for (int it = 0; it < 2; ++it) {
        int i = j * 4 + it * 256;
        *(int4*)&sX[i] = *(const int4*)&x[row * Tn + i];
    }

    // W_hh rows 2j, 2j+1 -> fp16 half2 regs (one-time; W is L2/L3-hot across blocks)
    half2v W0[64], W1[64];
    #pragma unroll
    for (int i = 0; i < 32; ++i) {
        float4 a = *(const float4*)&W_hh[(2 * j)     * Hn + 4 * i];
        float4 b = *(const float4*)&W_hh[(2 * j + 1) * Hn + 4 * i];
        W0[2 * i]     = half2v{(_Float16)a.x, (_Float16)a.y};
        W0[2 * i + 1] = half2v{(_Float16)a.z, (_Float16)a.w};
        W1[2 * i]     = half2v{(_Float16)b.x, (_Float16)b.y};
        W1[2 * i + 1] = half2v{(_Float16)b.z, (_Float16)b.w};
    }
    __syncthreads();   // sX visible (cheap: single wave)

    // h state (replicated, fp16-packed) in 64 regs; h0 = 0
    unsigned h32[64];
    #pragma unroll
    for (int i = 0; i < 64; ++i) h32[i] = 0u;

    // 2-deep id/proj prefetch pipeline
    int id_cur = sX[0];
    int id_nxt = sX[(len > 1) ? 1 : 0];
    float2 pj = *(const float2*)&proj[id_cur * Hn + 2 * j];

    float hf0 = 0.0f, hf1 = 0.0f;

    for (int t = 0; t < len; ++t) {
        // prefetch proj for t+1 (coalesced 8B/lane) and id for t+2
        float2 pj_n = *(const float2*)&proj[id_nxt * Hn + 2 * j];
        int id2 = sX[(t + 2 < len) ? (t + 2) : (len - 1)];

        // acc = proj + W_hh(rows 2j,2j+1) . h   -- 4 independent dot2 chains
        float a0e = pj.x, a0o = 0.0f, a1e = pj.y, a1o = 0.0f;
        #pragma unroll
        for (int i = 0; i < 64; i += 2) {
            half2v h0 = as_h2(h32[i]);
            half2v h1 = as_h2(h32[i + 1]);
            a0e = __builtin_amdgcn_fdot2(W0[i],     h0, a0e, false);
            a1e = __builtin_amdgcn_fdot2(W1[i],     h0, a1e, false);
            a0o = __builtin_amdgcn_fdot2(W0[i + 1], h1, a0o, false);
            a1o = __builtin_amdgcn_fdot2(W1[i + 1], h1, a1o, false);
        }
        hf0 = fast_tanh(a0e + a0o);
        hf1 = fast_tanh(a1e + a1o);

        // publish h (1 x b32 per lane) then re-replicate (16 broadcast b128)
        sH[j] = pack_h2(hf0, hf1);
        #pragma unroll
        for (int i = 0; i < 16; ++i) {
            uint4 v = *(const uint4*)&sH[4 * i];
            h32[4 * i]     = v.x;
            h32[4 * i + 1] = v.y;
            h32[4 * i + 2] = v.z;
            h32[4 * i + 3] = v.w;
        }

        pj = pj_n;
        id_nxt = id2;
    }

    // ---- head: logits = relu(h) @ W_out^T + b_out, log_softmax
    *(float2*)&sHf[2 * j] = make_float2(hf0, hf1);
    __syncthreads();

    if (j < On) {
        float acc = b_out[j];
        #pragma unroll 8
        for (int k = 0; k < Hn; ++k) {
            float hv = sHf[k];
            hv = hv > 0.0f ? hv : 0.0f;
            acc = fmaf(hv, W_out[j * Hn + k], acc);
        }
        sLog[j] = acc;
    }
    __syncthreads();

    if (j == 0) {
        float m = -INFINITY;
        #pragma unroll
        for (int c = 0; c < On; ++c) m = fmaxf(m, sLog[c]);
        float s = 0.0f;
        #pragma unroll
        for (int c = 0; c < On; ++c) s += __expf(sLog[c] - m);
        sRed[0] = m + __logf(s);
    }
    __syncthreads();

    if (j < On) out[row * On + j] = sLog[j] - sRed[0];
}

extern "C" void kernel_launch(void* const* d_in, const int* in_sizes, int n_in,
                              void* d_out, int out_size, void* d_ws, size_t ws_size,
                              hipStream_t stream) {
    const int*   x     = (const int*)d_in[0];
    const int*   xlen  = (const int*)d_in[1];
    const float* emb   = (const float*)d_in[2];
    const float* W_ih  = (const float*)d_in[3];
    const float* W_hh  = (const float*)d_in[4];
    const float* b_ih  = (const float*)d_in[5];
    const float* b_hh  = (const float*)d_in[6];
    const float* W_out = (const float*)d_in[7];
    const float* b_out = (const float*)d_in[8];
    float*       out   = (float*)d_out;
    float*       proj  = (float*)d_ws;   // 57*128*4 = 29,184 B

    proj_kernel<<<(Vn * Hn + 255) / 256, 256, 0, stream>>>(emb, W_ih, b_ih, b_hh, proj);
    rnn_row_kernel<<<Bn, 64, 0, stream>>>(x, xlen, W_hh, W_out, b_out, proj, out);
}